// Round 10
// baseline (14265.479 us; speedup 1.0000x reference)
//
#include <hip/hip_runtime.h>
#include <hip/hip_bf16.h>
#include <math.h>

// ---------------------------------------------------------------------------
// Stacked LSTM S=512, B=64, I=512, H=1024, L=4 — SEQUENTIAL per-layer
// persistent cooperative kernels.
// R6 (PASS 16.5ms): write-through h publish + coherence-point reads.
// R7/R8 (NEUTRAL): poll storm / load serialization falsified.
// R9 (WIN 14.2ms): h reads plain/L2-cacheable (write-once buffers per layer)
//     -> IF$ read amplification removed.
// Round-10 deltas (two independent, mechanistically-clear fixes):
//  1) hid32 (f32 output copy) store REMOVED from the last layer's critical
//     path: profile showed Lb1 dispatches ~0.45ms slower than others; the
//     f32 HBM store was drained by bar_arrive's syncthreads EVERY step.
//     The f32 output is now produced by a ~70us f16->f32 post-pass.
//  2) Barrier SPLIT by batch half: rows 0-31 (bg=0) and 32-63 (bg=1) are
//     independent recurrences (LSTM is batch-elementwise in h). Two
//     128-WG barriers (8 counters x 16 WGs each) halve fan-in and decouple
//     skew between halves. Publish/consume path unchanged (proven).
// ---------------------------------------------------------------------------

typedef _Float16 f16x8 __attribute__((ext_vector_type(8)));
typedef _Float16 f16x4 __attribute__((ext_vector_type(4)));
typedef float    f32x4 __attribute__((ext_vector_type(4)));

#define S_LEN 512
#define BATCH 64
#define HID   1024
#define GATES 4096
#define NCNT  8          // counters per batch-half
#define CNT_STRIDE 32    // ints -> 128 B per counter line
#define CNT_PER_LAYER (2 * NCNT * CNT_STRIDE)

// ---------------- prep kernels ----------------

__global__ void conv_f32_f16(const float4* __restrict__ in,
                             f16x4* __restrict__ out, int n4) {
  int i = blockIdx.x * blockDim.x + threadIdx.x;
  if (i < n4) {
    float4 v = in[i];
    f16x4 o;
    o[0] = (_Float16)v.x; o[1] = (_Float16)v.y;
    o[2] = (_Float16)v.z; o[3] = (_Float16)v.w;
    out[i] = o;
  }
}

// f16 -> f32 widening copy (for the hidden-seq output post-pass)
__global__ void conv_f16_f32(const f16x4* __restrict__ in,
                             float4* __restrict__ out, int n4) {
  int i = blockIdx.x * blockDim.x + threadIdx.x;
  if (i < n4) {
    f16x4 v = in[i];
    float4 o;
    o.x = (float)v[0]; o.y = (float)v[1];
    o.z = (float)v[2]; o.w = (float)v[3];
    out[i] = o;
  }
}

// dst[col][dstOff + k] = (f16) src[k][col], src is [srcK][4096] fp32 row-major.
__global__ void transpose_w(const float* __restrict__ src, int srcK,
                            _Float16* __restrict__ dst, int dstStride, int dstOff) {
  __shared__ float tile[64][65];
  const int kc0 = blockIdx.y * 64;
  const int c0  = blockIdx.x * 64;
  const int tid = threadIdx.x;
  const int r4  = tid >> 6;
  const int cc  = tid & 63;
#pragma unroll
  for (int i = 0; i < 16; ++i) {
    int r = i * 4 + r4;
    tile[r][cc] = src[(size_t)(kc0 + r) * 4096 + c0 + cc];
  }
  __syncthreads();
#pragma unroll
  for (int i = 0; i < 16; ++i) {
    int c = i * 4 + r4;
    dst[(size_t)(c0 + c) * dstStride + dstOff + kc0 + cc] = (_Float16)tile[cc][c];
  }
}

// ---------------- split counter barrier (per batch-half) ----------------
// Each half (bg) has NCNT counters x 16 WGs. Monotone, no reset.

__device__ __forceinline__ void bar_arrive(int* cnt, int bg, int cg) {
  __syncthreads();  // drains vmcnt -> write-through h stores durable at IF$
  if (threadIdx.x == 0)
    __hip_atomic_fetch_add(&cnt[(bg * NCNT + (cg >> 4)) * CNT_STRIDE], 1,
                           __ATOMIC_RELAXED, __HIP_MEMORY_SCOPE_AGENT);
}

__device__ __forceinline__ void bar_wait(int* cnt, int bg, int phase) {
  if (threadIdx.x < NCNT) {
    const int target = phase * 16;
    while (__hip_atomic_load(&cnt[(bg * NCNT + threadIdx.x) * CNT_STRIDE],
                             __ATOMIC_RELAXED,
                             __HIP_MEMORY_SCOPE_AGENT) < target)
      __builtin_amdgcn_s_sleep(2);
  }
  __syncthreads();
}

// ---------------- persistent per-layer LSTM kernel ----------------

template <int KX>
__launch_bounds__(256, 1)
__global__ void lstm_layer(const _Float16* __restrict__ inseq,  // [512][64][KX]
                           _Float16* outseq,                    // [512][64][1024]
                           const _Float16* __restrict__ WT,     // [4096][KX+1024]
                           const float* __restrict__ bias,      // [4096]
                           float* __restrict__ hfin,            // [64][1024]
                           float* __restrict__ cfin,            // [64][1024]
                           int* __restrict__ flags) {           // counters
  constexpr int KTOT = KX + 1024;
  constexpr int XI = KX / 128;
  constexpr int HI = 8;

  const int tid  = threadIdx.x;
  const int lane = tid & 63;
  const int w    = tid >> 6;
  const int n    = lane & 15;
  const int q    = lane >> 4;
  const int cg   = blockIdx.x >> 1;
  const int bg   = blockIdx.x & 1;

  __shared__ float zred[4][32][33];

  // B fragments (wave w holds K-quarter of the WG's 32 packed gate-cols)
  f16x8 bx[XI][2], bh[HI][2];
#pragma unroll
  for (int ct = 0; ct < 2; ++ct) {
    const int p  = ct * 16 + n;
    const int sc = (p >> 3) * 1024 + cg * 8 + (p & 7);
    const _Float16* base = WT + (size_t)sc * KTOT;
#pragma unroll
    for (int i = 0; i < XI; ++i)
      bx[i][ct] = *(const f16x8*)(base + w * (KX / 4) + i * 32 + q * 8);
#pragma unroll
    for (int i = 0; i < HI; ++i)
      bh[i][ct] = *(const f16x8*)(base + KX + w * 256 + i * 32 + q * 8);
  }

  const int erow  = tid >> 3;
  const int ejl   = tid & 7;
  const int grow  = bg * 32 + erow;
  const int ghcol = cg * 8 + ejl;
  const float bi  = bias[ghcol];
  const float bf  = bias[1024 + ghcol];
  const float bgg = bias[2048 + ghcol];
  const float bo  = bias[3072 + ghcol];
  float creg = 0.0f;

  const int arow0 = bg * 32 + n;
  const int arow1 = bg * 32 + 16 + n;

  for (int t = 0; t < S_LEN; ++t) {
    f32x4 acc00 = {}, acc01 = {}, acc10 = {}, acc11 = {};

    // ---- x part (independent of the recurrence -> issued BEFORE the wait)
    {
      const _Float16* xt = inseq + (size_t)t * BATCH * KX;
      const _Float16* a0p = xt + (size_t)arow0 * KX + w * (KX / 4) + q * 8;
      const _Float16* a1p = xt + (size_t)arow1 * KX + w * (KX / 4) + q * 8;
#pragma unroll
      for (int i = 0; i < XI; ++i) {
        f16x8 a0 = *(const f16x8*)(a0p + i * 32);
        f16x8 a1 = *(const f16x8*)(a1p + i * 32);
        acc00 = __builtin_amdgcn_mfma_f32_16x16x32_f16(a0, bx[i][0], acc00, 0, 0, 0);
        acc01 = __builtin_amdgcn_mfma_f32_16x16x32_f16(a0, bx[i][1], acc01, 0, 0, 0);
        acc10 = __builtin_amdgcn_mfma_f32_16x16x32_f16(a1, bx[i][0], acc10, 0, 0, 0);
        acc11 = __builtin_amdgcn_mfma_f32_16x16x32_f16(a1, bx[i][1], acc11, 0, 0, 0);
      }
    }

    // ---- wait for h_{t-1} from THIS batch-half's producers, then PLAIN
    // (L2-cacheable) batched h loads (write-once + barrier-ordered => fresh).
    if (t > 0) {
      bar_wait(flags, bg, t);
      const _Float16* hp = outseq + (size_t)(t - 1) * BATCH * HID;
      const _Float16* a0p = hp + (size_t)arow0 * HID + w * 256 + q * 8;
      const _Float16* a1p = hp + (size_t)arow1 * HID + w * 256 + q * 8;
      f16x8 ha0[HI], ha1[HI];
#pragma unroll
      for (int i = 0; i < HI; ++i) {
        ha0[i] = *(const f16x8*)(a0p + i * 32);
        ha1[i] = *(const f16x8*)(a1p + i * 32);
      }
#pragma unroll
      for (int i = 0; i < HI; ++i) {
        acc00 = __builtin_amdgcn_mfma_f32_16x16x32_f16(ha0[i], bh[i][0], acc00, 0, 0, 0);
        acc01 = __builtin_amdgcn_mfma_f32_16x16x32_f16(ha0[i], bh[i][1], acc01, 0, 0, 0);
        acc10 = __builtin_amdgcn_mfma_f32_16x16x32_f16(ha1[i], bh[i][0], acc10, 0, 0, 0);
        acc11 = __builtin_amdgcn_mfma_f32_16x16x32_f16(ha1[i], bh[i][1], acc11, 0, 0, 0);
      }
    }

    // ---- K-partial reduce through LDS (C/D: row=q*4+r, col=ct*16+n)
#pragma unroll
    for (int r = 0; r < 4; ++r) {
      zred[w][q * 4 + r][n]           = acc00[r];
      zred[w][q * 4 + r][16 + n]      = acc01[r];
      zred[w][16 + q * 4 + r][n]      = acc10[r];
      zred[w][16 + q * 4 + r][16 + n] = acc11[r];
    }
    __syncthreads();

    float zi = bi, zf = bf, zg = bgg, zo = bo;
#pragma unroll
    for (int ww = 0; ww < 4; ++ww) {
      zi += zred[ww][erow][ejl];
      zf += zred[ww][erow][8 + ejl];
      zg += zred[ww][erow][16 + ejl];
      zo += zred[ww][erow][24 + ejl];
    }
    float ig = 1.0f / (1.0f + __expf(-zi));
    float fg = 1.0f / (1.0f + __expf(-zf));
    float gg = tanhf(zg);
    float og = 1.0f / (1.0f + __expf(-zo));
    float cn = fg * creg + ig * gg;
    float h  = og * tanhf(cn);
    creg = cn;

    const size_t oidx = (size_t)grow * HID + ghcol;

    // ---- h publish: pack 2 adjacent cols (tid, tid^1 same wave) into one
    // 4B write-through relaxed agent atomic store (no dirty-L2 h lines).
    {
      _Float16 hh = (_Float16)h;
      unsigned short hb = __builtin_bit_cast(unsigned short, hh);
      unsigned short pb = (unsigned short)__shfl_xor((int)hb, 1, 64);
      if ((ejl & 1) == 0) {
        unsigned int packed = (unsigned int)hb | ((unsigned int)pb << 16);
        unsigned int* dst =
            (unsigned int*)(outseq + (size_t)t * BATCH * HID + oidx);
        __hip_atomic_store(dst, packed, __ATOMIC_RELAXED,
                           __HIP_MEMORY_SCOPE_AGENT);
      }
    }
    if (t == S_LEN - 1) { hfin[oidx] = h; cfin[oidx] = cn; }

    if (t + 1 < S_LEN) bar_arrive(flags, bg, cg);  // publish h_t
    else __syncthreads();
  }
}

// ---------------- host ----------------

extern "C" void kernel_launch(void* const* d_in, const int* in_sizes, int n_in,
                              void* d_out, int out_size, void* d_ws, size_t ws_size,
                              hipStream_t stream) {
  const float* x_f32   = (const float*)d_in[0];
  const float* Wx0     = (const float*)d_in[1];
  const float* Wh0     = (const float*)d_in[2];
  const float* b0      = (const float*)d_in[3];
  const float* Wx_rest = (const float*)d_in[4];
  const float* Wh_rest = (const float*)d_in[5];
  const float* b_rest  = (const float*)d_in[6];

  float* out = (float*)d_out;
  float* hid_seq = out;                                     // [512,64,1024]
  float* h_fin   = out + (size_t)S_LEN * BATCH * HID;       // [4,64,1024]
  float* c_fin   = h_fin + (size_t)4 * BATCH * HID;         // [4,64,1024]

  size_t off = 0;
  auto alloc = [&](size_t bytes) {
    void* p = (char*)d_ws + off;
    off += (bytes + 255) & ~(size_t)255;
    return p;
  };
  _Float16* WT[4];
  WT[0] = (_Float16*)alloc((size_t)GATES * 1536 * 2);
  WT[1] = (_Float16*)alloc((size_t)GATES * 2048 * 2);
  WT[2] = (_Float16*)alloc((size_t)GATES * 2048 * 2);
  WT[3] = (_Float16*)alloc((size_t)GATES * 2048 * 2);
  _Float16* x16  = (_Float16*)alloc((size_t)S_LEN * BATCH * 512 * 2);
  // one DISTINCT h buffer per layer: no cross-launch address reuse
  _Float16* seq[4];
  for (int l = 0; l < 4; ++l)
    seq[l] = (_Float16*)alloc((size_t)S_LEN * BATCH * HID * 2);
  int* flags     = (int*)alloc(4 * CNT_PER_LAYER * sizeof(int));

  // zero barrier counters (ws is poisoned to 0xAA before every call)
  hipMemsetAsync(flags, 0, 4 * CNT_PER_LAYER * sizeof(int), stream);

  // convert x to fp16
  {
    int n4 = S_LEN * BATCH * 512 / 4;
    conv_f32_f16<<<dim3((n4 + 255) / 256), dim3(256), 0, stream>>>(
        (const float4*)x_f32, (f16x4*)x16, n4);
  }

  // fused transposed weights: WT_l[col][k], x rows then h rows
  transpose_w<<<dim3(64, 512 / 64), dim3(256), 0, stream>>>(Wx0, 512, WT[0], 1536, 0);
  transpose_w<<<dim3(64, 1024 / 64), dim3(256), 0, stream>>>(Wh0, 1024, WT[0], 1536, 512);
  for (int l = 1; l < 4; ++l) {
    const float* wx = Wx_rest + (size_t)(l - 1) * 1024 * 4096;
    const float* wh = Wh_rest + (size_t)(l - 1) * 1024 * 4096;
    transpose_w<<<dim3(64, 1024 / 64), dim3(256), 0, stream>>>(wx, 1024, WT[l], 2048, 0);
    transpose_w<<<dim3(64, 1024 / 64), dim3(256), 0, stream>>>(wh, 1024, WT[l], 2048, 1024);
  }

  struct LayerCfg {
    const _Float16* in; _Float16* outp; const _Float16* wt; const float* b;
    float* hf; float* cf; int* flg; int kx;
  } cfg[4] = {
    { x16,    seq[0], WT[0], b0,              h_fin + 0 * 65536, c_fin + 0 * 65536, flags + 0 * CNT_PER_LAYER, 512 },
    { seq[0], seq[1], WT[1], b_rest + 0*4096, h_fin + 1 * 65536, c_fin + 1 * 65536, flags + 1 * CNT_PER_LAYER, 1024 },
    { seq[1], seq[2], WT[2], b_rest + 1*4096, h_fin + 2 * 65536, c_fin + 2 * 65536, flags + 2 * CNT_PER_LAYER, 1024 },
    { seq[2], seq[3], WT[3], b_rest + 2*4096, h_fin + 3 * 65536, c_fin + 3 * 65536, flags + 3 * CNT_PER_LAYER, 1024 },
  };

  for (int l = 0; l < 4; ++l) {
    const _Float16* pin = cfg[l].in;
    _Float16* pout = cfg[l].outp;
    const _Float16* pwt = cfg[l].wt;
    const float* pb = cfg[l].b;
    float* phf = cfg[l].hf;
    float* pcf = cfg[l].cf;
    int* pfl = cfg[l].flg;
    void* args[7] = { &pin, &pout, &pwt, &pb, &phf, &pcf, &pfl };
    if (cfg[l].kx == 512) {
      hipLaunchCooperativeKernel(reinterpret_cast<void*>(&lstm_layer<512>),
                                 dim3(256), dim3(256), args, 0, stream);
    } else {
      hipLaunchCooperativeKernel(reinterpret_cast<void*>(&lstm_layer<1024>),
                                 dim3(256), dim3(256), args, 0, stream);
    }
  }

  // post-pass: widen layer-3 h (f16) to the f32 hidden-seq output.
  {
    int n4 = S_LEN * BATCH * HID / 4;
    conv_f16_f32<<<dim3((n4 + 255) / 256), dim3(256), 0, stream>>>(
        (const f16x4*)seq[3], (float4*)hid_seq, n4);
  }
}